// Round 12
// baseline (281.089 us; speedup 1.0000x reference)
//
#include <hip/hip_runtime.h>
#include <hip/hip_fp16.h>
#include <math.h>

#define HF 64
#define LEAKY 0.2f
#define NBLK 256          // partition blocks
#define NPB 512           // nodes per bucket (bucket = dst >> 9)
#define MAXNB 256         // static LDS sizing for bucket counters

typedef _Float16 f16x2 __attribute__((ext_vector_type(2)));

__device__ __forceinline__ float dot2f(f16x2 a, f16x2 b, float c) {
#if __has_builtin(__builtin_amdgcn_fdot2)
    return __builtin_amdgcn_fdot2(a, b, c, false);
#else
    return fmaf((float)a[0], (float)b[0], fmaf((float)a[1], (float)b[1], c));
#endif
}

// ---------------- CSR build: two-level bucket partition ----------------

__global__ __launch_bounds__(256)
void part_count(const int* __restrict__ dst, int* __restrict__ Cmat, int E, int nb) {
    __shared__ int lc[MAXNB];
    int tid = threadIdx.x;
    for (int t = tid; t < nb; t += 256) lc[t] = 0;
    __syncthreads();
    int chunk = (E + NBLK - 1) / NBLK;
    int b0 = blockIdx.x * chunk, b1 = min(b0 + chunk, E);
    for (int i = b0 + tid; i < b1; i += 256)
        atomicAdd(&lc[dst[i] >> 9], 1);
    __syncthreads();
    for (int t = tid; t < nb; t += 256) Cmat[t * NBLK + blockIdx.x] = lc[t];
}

__global__ __launch_bounds__(256)
void scan_offsets(const int* __restrict__ Cmat, int* __restrict__ Omat,
                  int* __restrict__ bbase, int E, int nb) {
    __shared__ int tot[256];
    int t = threadIdx.x;
    int s = 0;
    if (t < nb)
        for (int blk = 0; blk < NBLK; ++blk) s += Cmat[t * NBLK + blk];
    tot[t] = s;
    __syncthreads();
    for (int off = 1; off < 256; off <<= 1) {
        int u = (t >= off) ? tot[t - off] : 0;
        __syncthreads();
        tot[t] += u;
        __syncthreads();
    }
    int excl = tot[t] - s;
    if (t < nb) {
        bbase[t] = excl;
        int run = excl;
        for (int blk = 0; blk < NBLK; ++blk) {
            Omat[t * NBLK + blk] = run;
            run += Cmat[t * NBLK + blk];
        }
    }
    if (t == 0) bbase[nb] = E;
}

__global__ __launch_bounds__(256)
void part_scatter(const int* __restrict__ src, const int* __restrict__ dst,
                  const int* __restrict__ Omat, int2* __restrict__ part, int E, int nb) {
    __shared__ int ocur[MAXNB];
    int tid = threadIdx.x;
    for (int t = tid; t < nb; t += 256) ocur[t] = Omat[t * NBLK + blockIdx.x];
    __syncthreads();
    int chunk = (E + NBLK - 1) / NBLK;
    int b0 = blockIdx.x * chunk, b1 = min(b0 + chunk, E);
    for (int i = b0 + tid; i < b1; i += 256) {
        int s = src[i], d = dst[i];
        int pos = atomicAdd(&ocur[d >> 9], 1);
        part[pos] = make_int2(s, d);
    }
}

__global__ __launch_bounds__(NPB)
void bucket_csr(const int2* __restrict__ part, const int* __restrict__ bbase,
                int* __restrict__ row_ptr, int* __restrict__ ssrc, int N, int E, int nb) {
    int b = blockIdx.x, tid = threadIdx.x;
    int bstart = bbase[b], bend = bbase[b + 1];
    int nb0 = b << 9;
    __shared__ int cnt[NPB];
    cnt[tid] = 0;
    __syncthreads();
    for (int i = bstart + tid; i < bend; i += NPB)
        atomicAdd(&cnt[part[i].y & (NPB - 1)], 1);
    __syncthreads();
    int v = cnt[tid];
    for (int off = 1; off < NPB; off <<= 1) {
        int u = (tid >= off) ? cnt[tid - off] : 0;
        __syncthreads();
        cnt[tid] += u;
        __syncthreads();
    }
    int excl = cnt[tid] - v;
    int node = nb0 + tid;
    if (node < N) row_ptr[node] = bstart + excl;
    __syncthreads();
    cnt[tid] = bstart + excl;
    __syncthreads();
    for (int i = bstart + tid; i < bend; i += NPB) {
        int2 e = part[i];
        int slot = atomicAdd(&cnt[e.y & (NPB - 1)], 1);
        ssrc[slot] = e.x;
    }
    if (b == nb - 1 && tid == 0) row_ptr[N] = E;
}

// ---------------- GEMM: H2(fp16) = X @ W, el = H a_l, er = H a_r ----------------
// PERSISTENT blocks (~3 tiles each, whole grid co-resident), W staged once per
// block, X double-buffered: issue tile t+1 global loads -> compute tile t from
// LDS -> epilogue -> convert+ds_write t+1 -> one barrier. Hides global latency
// under dot2 compute (round-11 version serialized stage->sync->compute per
// block; time was K-independent => per-block latency dominated).
// XF16: input already fp16 (Y of previous layer) -> staging is a bit-copy.

template <int K, bool XF16>
__global__ __launch_bounds__(256)
void gemm_kernel(const void* __restrict__ Xv, const float* __restrict__ W,
                 const float* __restrict__ al, const float* __restrict__ ar,
                 __half* __restrict__ H2, float* __restrict__ el, float* __restrict__ er,
                 int n, int ntiles) {
    constexpr int K2 = K / 2;
    constexpr int F4 = K / 4;        // 4-element groups per row
    constexpr int NL = 64 * F4 / 256; // loads per thread per tile (8 for K=128)
    __shared__ f16x2 Wh[K2 * 64];
    __shared__ f16x2 Xh[2][64 * K2];
    int tid = threadIdx.x;

    int tpb = (ntiles + gridDim.x - 1) / gridDim.x;
    int t0 = blockIdx.x * tpb, t1 = min(t0 + tpb, ntiles);
    if (t0 >= t1) return;

    // stage W once: pack (W[2k2][c], W[2k2+1][c])
    for (int idx = tid; idx < K2 * 64; idx += 256) {
        int k2 = idx >> 6, c = idx & 63;
        f16x2 h;
        h[0] = (_Float16)W[(2 * k2) * 64 + c];
        h[1] = (_Float16)W[(2 * k2 + 1) * 64 + c];
        Wh[idx] = h;
    }

    float4 xregf[XF16 ? 1 : NL];
    uint2 xregh[XF16 ? NL : 1];

    auto load_regs = [&](int t) {
        int rb = t * 64;
#pragma unroll
        for (int j = 0; j < NL; ++j) {
            int idx = tid + j * 256;
            int row = idx / F4;
            bool ok = rb + row < n;
            if constexpr (XF16) {
                uint2 z = make_uint2(0u, 0u);
                xregh[j] = ok ? ((const uint2*)Xv)[(size_t)rb * (K / 4) + idx] : z;
            } else {
                float4 z = make_float4(0.f, 0.f, 0.f, 0.f);
                xregf[j] = ok ? ((const float4*)Xv)[(size_t)rb * (K / 4) + idx] : z;
            }
        }
    };
    auto store_X = [&](int buf) {
#pragma unroll
        for (int j = 0; j < NL; ++j) {
            int idx = tid + j * 256;
            int row = idx / F4, k4 = idx % F4;
            int sw = (row & 15) << 1;
            f16x2 h0, h1;
            if constexpr (XF16) {
                h0 = *(f16x2*)&xregh[j].x;
                h1 = *(f16x2*)&xregh[j].y;
            } else {
                h0[0] = (_Float16)xregf[j].x; h0[1] = (_Float16)xregf[j].y;
                h1[0] = (_Float16)xregf[j].z; h1[1] = (_Float16)xregf[j].w;
            }
            Xh[buf][row * K2 + ((2 * k4) ^ sw)] = h0;
            Xh[buf][row * K2 + ((2 * k4 + 1) ^ sw)] = h1;
        }
    };

    int tc = tid & 15, tr = tid >> 4;
    float alv[4], arv[4];
#pragma unroll
    for (int i = 0; i < 4; ++i) { alv[i] = al[tc * 4 + i]; arv[i] = ar[tc * 4 + i]; }

    load_regs(t0);
    store_X(0);
    __syncthreads();
    int cur = 0;

    for (int t = t0; t < t1; ++t) {
        bool pf = (t + 1 < t1);
        if (pf) load_regs(t + 1);            // global loads in flight during compute

        float acc[4][4] = {};
#pragma unroll 4
        for (int k2 = 0; k2 < K2; k2 += 2) {
            f16x2 xa[4], xb[4];
#pragma unroll
            for (int r = 0; r < 4; ++r) {
                int row = tr * 4 + r;
                int sw = (row & 15) << 1;
                const f16x2* p = &Xh[cur][row * K2 + (k2 ^ sw)];
                xa[r] = p[0];
                xb[r] = p[1];
            }
            const f16x2* w0 = &Wh[k2 * 64 + tc * 4];
            const f16x2* w1 = &Wh[(k2 + 1) * 64 + tc * 4];
#pragma unroll
            for (int i = 0; i < 4; ++i) {
                f16x2 wv0 = w0[i], wv1 = w1[i];
#pragma unroll
                for (int r = 0; r < 4; ++r) {
                    acc[r][i] = dot2f(xa[r], wv0, acc[r][i]);
                    acc[r][i] = dot2f(xb[r], wv1, acc[r][i]);
                }
            }
        }

        // epilogue for tile t
        int r0 = t * 64 + tr * 4;
#pragma unroll
        for (int r = 0; r < 4; ++r) {
            if (r0 + r >= n) continue;
            __half2 h01 = __floats2half2_rn(acc[r][0], acc[r][1]);
            __half2 h23 = __floats2half2_rn(acc[r][2], acc[r][3]);
            uint2 u = make_uint2(*(unsigned*)&h01, *(unsigned*)&h23);
            ((uint2*)(H2 + (size_t)(r0 + r) * HF))[tc] = u;
            float pl = acc[r][0] * alv[0] + acc[r][1] * alv[1] + acc[r][2] * alv[2] + acc[r][3] * alv[3];
            float pr = acc[r][0] * arv[0] + acc[r][1] * arv[1] + acc[r][2] * arv[2] + acc[r][3] * arv[3];
#pragma unroll
            for (int off = 1; off < 16; off <<= 1) {
                pl += __shfl_xor(pl, off);
                pr += __shfl_xor(pr, off);
            }
            if (tc == 0) { el[r0 + r] = pl; er[r0 + r] = pr; }
        }

        if (pf) store_X(cur ^ 1);            // waits vmcnt, writes other buffer
        __syncthreads();
        if (pf) cur ^= 1;
    }
}

// ---------------- Edge phase ----------------
template <bool YF16>
__device__ __forceinline__
void node_fullwave(int node, const int* __restrict__ row_ptr, const int* __restrict__ ssrc,
                   const float* __restrict__ el, const float* __restrict__ er,
                   const uint2* __restrict__ H2v, const __half* __restrict__ H2,
                   float4 bv, const float* __restrict__ b, void* __restrict__ Y,
                   int lane, int g, int fl) {
    int s0 = row_ptr[node], s1 = row_ptr[node + 1];
    int d = s1 - s0;
    float ern = er[node];

    if (d <= 64) {
        int sidx = 0;
        float e = -INFINITY;
        if (lane < d) {
            sidx = ssrc[s0 + lane];
            e = el[sidx] + ern;
            e = e > 0.f ? e : LEAKY * e;
        }
        float m = e;
#pragma unroll
        for (int off = 32; off; off >>= 1) m = fmaxf(m, __shfl_xor(m, off));
        float p = (lane < d) ? __expf(e - m) : 0.f;
        float psum = p;
#pragma unroll
        for (int off = 32; off; off >>= 1) psum += __shfl_xor(psum, off);

        float4 acc = make_float4(0.f, 0.f, 0.f, 0.f);
        int nchunk = (d + 31) >> 5;
        for (int c = 0; c < nchunk; ++c) {
            int jb = c * 32 + g;
            int ss[8];
            float pp[8];
#pragma unroll
            for (int u = 0; u < 8; ++u) {
                ss[u] = __shfl(sidx, jb + 4 * u);
                pp[u] = __shfl(p, jb + 4 * u);
            }
            uint2 vv[8];
#pragma unroll
            for (int u = 0; u < 8; ++u) vv[u] = H2v[(size_t)ss[u] * 16 + fl];
#pragma unroll
            for (int u = 0; u < 8; ++u) {
                __half2 a = *(__half2*)&vv[u].x;
                __half2 b2 = *(__half2*)&vv[u].y;
                float2 fa = __half22float2(a);
                float2 fb = __half22float2(b2);
                acc.x = fmaf(pp[u], fa.x, acc.x);
                acc.y = fmaf(pp[u], fa.y, acc.y);
                acc.z = fmaf(pp[u], fb.x, acc.z);
                acc.w = fmaf(pp[u], fb.y, acc.w);
            }
        }
#pragma unroll
        for (int off = 16; off <= 32; off <<= 1) {
            acc.x += __shfl_xor(acc.x, off);
            acc.y += __shfl_xor(acc.y, off);
            acc.z += __shfl_xor(acc.z, off);
            acc.w += __shfl_xor(acc.w, off);
        }
        float inv = d ? 1.f / psum : 0.f;
        float4 o;
        o.x = fmaf(acc.x, inv, bv.x);
        o.y = fmaf(acc.y, inv, bv.y);
        o.z = fmaf(acc.z, inv, bv.z);
        o.w = fmaf(acc.w, inv, bv.w);
        o.x = o.x > 0.f ? o.x : 0.f;
        o.y = o.y > 0.f ? o.y : 0.f;
        o.z = o.z > 0.f ? o.z : 0.f;
        o.w = o.w > 0.f ? o.w : 0.f;
        if (g == 0) {
            if constexpr (YF16) {
                __half2 a = __floats2half2_rn(o.x, o.y);
                __half2 c = __floats2half2_rn(o.z, o.w);
                ((uint2*)Y)[(size_t)node * 16 + fl] = make_uint2(*(unsigned*)&a, *(unsigned*)&c);
            } else {
                ((float4*)Y)[(size_t)node * 16 + fl] = o;
            }
        }
    } else {
        float m = -INFINITY;
        for (int j = s0 + lane; j < s1; j += 64) {
            float e = el[ssrc[j]] + ern;
            e = e > 0.f ? e : LEAKY * e;
            m = fmaxf(m, e);
        }
#pragma unroll
        for (int off = 32; off; off >>= 1) m = fmaxf(m, __shfl_xor(m, off));
        float acc = 0.f, psum = 0.f;
        for (int j = s0; j < s1; ++j) {
            int s = ssrc[j];
            float e = el[s] + ern;
            e = e > 0.f ? e : LEAKY * e;
            float p = __expf(e - m);
            psum += p;
            acc = fmaf(p, __half2float(H2[(size_t)s * HF + lane]), acc);
        }
        float o = acc / psum + b[lane];
        o = o > 0.f ? o : 0.f;
        if constexpr (YF16)
            ((__half*)Y)[(size_t)node * HF + lane] = __float2half(o);
        else
            ((float*)Y)[(size_t)node * HF + lane] = o;
    }
}

// Two nodes per wave (half-wave each); groups 0-1 node A, 2-3 node B.
template <bool YF16>
__global__ __launch_bounds__(256)
void edge_kernel(const int* __restrict__ row_ptr, const int* __restrict__ ssrc,
                 const float* __restrict__ el, const float* __restrict__ er,
                 const __half* __restrict__ H2, const float* __restrict__ b,
                 void* __restrict__ Y, int n) {
    int wave = threadIdx.x >> 6, lane = threadIdx.x & 63;
    int half = lane >> 5, hl = lane & 31;
    int g = lane >> 4, fl = lane & 15;
    const uint2* H2v = (const uint2*)H2;
    float4 bv = ((const float4*)b)[fl];
    int npairs = (n + 1) >> 1;

    for (int pr = blockIdx.x * 4 + wave; pr < npairs; pr += gridDim.x * 4) {
        int nodeA = pr * 2;
        int myNode = nodeA + half;
        bool ok = myNode < n;
        int s0 = 0, d = 0;
        if (ok) {
            s0 = row_ptr[myNode];
            d = row_ptr[myNode + 1] - s0;
        }
        int dA = __shfl(d, 0), dB = __shfl(d, 32);

        if (dA <= 32 && dB <= 32) {
            float ern = ok ? er[myNode] : 0.f;
            int sidx = 0;
            float e = -INFINITY;
            if (hl < d) {
                sidx = ssrc[s0 + hl];
                e = el[sidx] + ern;
                e = e > 0.f ? e : LEAKY * e;
            }
            float m = e;
#pragma unroll
            for (int off = 16; off; off >>= 1) m = fmaxf(m, __shfl_xor(m, off));
            float p = (hl < d) ? __expf(e - m) : 0.f;
            float psum = p;
#pragma unroll
            for (int off = 16; off; off >>= 1) psum += __shfl_xor(psum, off);

            float4 acc = make_float4(0.f, 0.f, 0.f, 0.f);
            int dg = (g >> 1) ? dB : dA;
            int hbase = (g >> 1) << 5;
            int gpar = g & 1;
            int nch = (dg + 15) >> 4;
            for (int c = 0; c < nch; ++c) {
                int ss[8];
                float pp[8];
#pragma unroll
                for (int u = 0; u < 8; ++u) {
                    int sl = hbase + c * 16 + 2 * u + gpar;
                    ss[u] = __shfl(sidx, sl);
                    pp[u] = __shfl(p, sl);
                }
                uint2 vv[8];
#pragma unroll
                for (int u = 0; u < 8; ++u) vv[u] = H2v[(size_t)ss[u] * 16 + fl];
#pragma unroll
                for (int u = 0; u < 8; ++u) {
                    __half2 a = *(__half2*)&vv[u].x;
                    __half2 b2 = *(__half2*)&vv[u].y;
                    float2 fa = __half22float2(a);
                    float2 fb = __half22float2(b2);
                    acc.x = fmaf(pp[u], fa.x, acc.x);
                    acc.y = fmaf(pp[u], fa.y, acc.y);
                    acc.z = fmaf(pp[u], fb.x, acc.z);
                    acc.w = fmaf(pp[u], fb.y, acc.w);
                }
            }
            acc.x += __shfl_xor(acc.x, 16);
            acc.y += __shfl_xor(acc.y, 16);
            acc.z += __shfl_xor(acc.z, 16);
            acc.w += __shfl_xor(acc.w, 16);
            float inv = d ? 1.f / psum : 0.f;
            float4 o;
            o.x = fmaf(acc.x, inv, bv.x);
            o.y = fmaf(acc.y, inv, bv.y);
            o.z = fmaf(acc.z, inv, bv.z);
            o.w = fmaf(acc.w, inv, bv.w);
            o.x = o.x > 0.f ? o.x : 0.f;
            o.y = o.y > 0.f ? o.y : 0.f;
            o.z = o.z > 0.f ? o.z : 0.f;
            o.w = o.w > 0.f ? o.w : 0.f;
            if (!(g & 1) && ok) {
                if constexpr (YF16) {
                    __half2 a = __floats2half2_rn(o.x, o.y);
                    __half2 c2 = __floats2half2_rn(o.z, o.w);
                    ((uint2*)Y)[(size_t)myNode * 16 + fl] = make_uint2(*(unsigned*)&a, *(unsigned*)&c2);
                } else {
                    ((float4*)Y)[(size_t)myNode * 16 + fl] = o;
                }
            }
        } else {
            node_fullwave<YF16>(nodeA, row_ptr, ssrc, el, er, H2v, H2, bv, b, Y, lane, g, fl);
            if (nodeA + 1 < n)
                node_fullwave<YF16>(nodeA + 1, row_ptr, ssrc, el, er, H2v, H2, bv, b, Y, lane, g, fl);
        }
    }
}

// ---------------- launch ----------------

extern "C" void kernel_launch(void* const* d_in, const int* in_sizes, int n_in,
                              void* d_out, int out_size, void* d_ws, size_t ws_size,
                              hipStream_t stream) {
    const int N = in_sizes[0] / 128;
    const int E = in_sizes[1];
    const int nb = (N + NPB - 1) >> 9;

    const float* in_feat = (const float*)d_in[0];
    const int* src = (const int*)d_in[1];
    const int* dst = (const int*)d_in[2];
    const float* W1 = (const float*)d_in[3];
    const float* al1 = (const float*)d_in[4];
    const float* ar1 = (const float*)d_in[5];
    const float* b1 = (const float*)d_in[6];
    const float* W2 = (const float*)d_in[7];
    const float* al2 = (const float*)d_in[8];
    const float* ar2 = (const float*)d_in[9];
    const float* b2 = (const float*)d_in[10];
    const float* W3 = (const float*)d_in[11];
    const float* al3 = (const float*)d_in[12];
    const float* ar3 = (const float*)d_in[13];
    const float* b3 = (const float*)d_in[14];

    char* ws = (char*)d_ws;
    size_t off = 0;
    auto alloc = [&](size_t bytes) {
        void* p = ws + off;
        off += (bytes + 255) & ~(size_t)255;
        return p;
    };
    int* row_ptr = (int*)alloc(((size_t)N + 1) * 4);
    int* ssrc = (int*)alloc((size_t)E * 4);
    int2* part = (int2*)alloc((size_t)E * 8);
    int* Cmat = (int*)alloc((size_t)MAXNB * NBLK * 4);
    int* Omat = (int*)alloc((size_t)MAXNB * NBLK * 4);
    int* bbase = (int*)alloc(((size_t)MAXNB + 1) * 4);
    float* el = (float*)alloc((size_t)N * 4);
    float* er = (float*)alloc((size_t)N * 4);
    __half* H2buf = (__half*)alloc((size_t)N * HF * 2);
    __half* Y2buf = (__half*)alloc((size_t)N * HF * 2);

    part_count<<<NBLK, 256, 0, stream>>>(dst, Cmat, E, nb);
    scan_offsets<<<1, 256, 0, stream>>>(Cmat, Omat, bbase, E, nb);
    part_scatter<<<NBLK, 256, 0, stream>>>(src, dst, Omat, part, E, nb);
    bucket_csr<<<nb, NPB, 0, stream>>>(part, bbase, row_ptr, ssrc, N, E, nb);

    int ntiles = (N + 63) / 64;
    int gg = (ntiles + 2) / 3;     // persistent gemm blocks, ~3 tiles each
    int ge = 2048;                 // persistent edge blocks

    // layer 1 (f32 in, fp16 Y out)
    gemm_kernel<128, false><<<gg, 256, 0, stream>>>(in_feat, W1, al1, ar1, H2buf, el, er, N, ntiles);
    edge_kernel<true><<<ge, 256, 0, stream>>>(row_ptr, ssrc, el, er, H2buf, b1, Y2buf, N);
    // layer 2 (fp16 in, fp16 Y out)
    gemm_kernel<64, true><<<gg, 256, 0, stream>>>(Y2buf, W2, al2, ar2, H2buf, el, er, N, ntiles);
    edge_kernel<true><<<ge, 256, 0, stream>>>(row_ptr, ssrc, el, er, H2buf, b2, Y2buf, N);
    // layer 3 (fp16 in, f32 out to d_out)
    gemm_kernel<64, true><<<gg, 256, 0, stream>>>(Y2buf, W3, al3, ar3, H2buf, el, er, N, ntiles);
    edge_kernel<false><<<ge, 256, 0, stream>>>(row_ptr, ssrc, el, er, H2buf, b3, d_out, N);
}

// Round 13
// 228.262 us; speedup vs baseline: 1.2314x; 1.2314x over previous
//
#include <hip/hip_runtime.h>
#include <hip/hip_fp16.h>
#include <math.h>

#define HF 64
#define LEAKY 0.2f
#define NBLK 256          // partition blocks
#define NPB 512           // nodes per bucket (bucket = dst >> 9)
#define MAXNB 256         // static LDS sizing for bucket counters

typedef _Float16 half4_t __attribute__((ext_vector_type(4)));
typedef _Float16 half8_t __attribute__((ext_vector_type(8)));
typedef float floatx4 __attribute__((ext_vector_type(4)));

// ---------------- CSR build: two-level bucket partition ----------------

__global__ __launch_bounds__(256)
void part_count(const int* __restrict__ dst, int* __restrict__ Cmat, int E, int nb) {
    __shared__ int lc[MAXNB];
    int tid = threadIdx.x;
    for (int t = tid; t < nb; t += 256) lc[t] = 0;
    __syncthreads();
    int chunk = (E + NBLK - 1) / NBLK;
    int b0 = blockIdx.x * chunk, b1 = min(b0 + chunk, E);
    for (int i = b0 + tid; i < b1; i += 256)
        atomicAdd(&lc[dst[i] >> 9], 1);
    __syncthreads();
    for (int t = tid; t < nb; t += 256) Cmat[t * NBLK + blockIdx.x] = lc[t];
}

__global__ __launch_bounds__(256)
void scan_offsets(const int* __restrict__ Cmat, int* __restrict__ Omat,
                  int* __restrict__ bbase, int E, int nb) {
    __shared__ int tot[256];
    int t = threadIdx.x;
    int s = 0;
    if (t < nb)
        for (int blk = 0; blk < NBLK; ++blk) s += Cmat[t * NBLK + blk];
    tot[t] = s;
    __syncthreads();
    for (int off = 1; off < 256; off <<= 1) {
        int u = (t >= off) ? tot[t - off] : 0;
        __syncthreads();
        tot[t] += u;
        __syncthreads();
    }
    int excl = tot[t] - s;
    if (t < nb) {
        bbase[t] = excl;
        int run = excl;
        for (int blk = 0; blk < NBLK; ++blk) {
            Omat[t * NBLK + blk] = run;
            run += Cmat[t * NBLK + blk];
        }
    }
    if (t == 0) bbase[nb] = E;
}

__global__ __launch_bounds__(256)
void part_scatter(const int* __restrict__ src, const int* __restrict__ dst,
                  const int* __restrict__ Omat, int2* __restrict__ part, int E, int nb) {
    __shared__ int ocur[MAXNB];
    int tid = threadIdx.x;
    for (int t = tid; t < nb; t += 256) ocur[t] = Omat[t * NBLK + blockIdx.x];
    __syncthreads();
    int chunk = (E + NBLK - 1) / NBLK;
    int b0 = blockIdx.x * chunk, b1 = min(b0 + chunk, E);
    for (int i = b0 + tid; i < b1; i += 256) {
        int s = src[i], d = dst[i];
        int pos = atomicAdd(&ocur[d >> 9], 1);
        part[pos] = make_int2(s, d);
    }
}

__global__ __launch_bounds__(NPB)
void bucket_csr(const int2* __restrict__ part, const int* __restrict__ bbase,
                int* __restrict__ row_ptr, int* __restrict__ ssrc, int N, int E, int nb) {
    int b = blockIdx.x, tid = threadIdx.x;
    int bstart = bbase[b], bend = bbase[b + 1];
    int nb0 = b << 9;
    __shared__ int cnt[NPB];
    cnt[tid] = 0;
    __syncthreads();
    for (int i = bstart + tid; i < bend; i += NPB)
        atomicAdd(&cnt[part[i].y & (NPB - 1)], 1);
    __syncthreads();
    int v = cnt[tid];
    for (int off = 1; off < NPB; off <<= 1) {
        int u = (tid >= off) ? cnt[tid - off] : 0;
        __syncthreads();
        cnt[tid] += u;
        __syncthreads();
    }
    int excl = cnt[tid] - v;
    int node = nb0 + tid;
    if (node < N) row_ptr[node] = bstart + excl;
    __syncthreads();
    cnt[tid] = bstart + excl;
    __syncthreads();
    for (int i = bstart + tid; i < bend; i += NPB) {
        int2 e = part[i];
        int slot = atomicAdd(&cnt[e.y & (NPB - 1)], 1);
        ssrc[slot] = e.x;
    }
    if (b == nb - 1 && tid == 0) row_ptr[N] = E;
}

// ---------------- GEMM via MFMA: H2(fp16) = X @ W, el/er fused ----------------
// One wave owns a 16-row slab x 64 cols: 4 accumulators (16x16 tiles), the
// ENTIRE W held as B-fragments in registers (loaded once per wave from L2,
// amortized over ~3 slabs via grid-stride). A-fragments stream from global
// (16B/lane). NO LDS, NO barriers. k-slot mapping: k = ks*32 + 4g + j (+16
// for upper half) used identically for A and B (any shared bijection is
// correct by permutation-invariance of the contraction).
// C/D layout (m89-verified): col = lane&15, row = (lane>>4)*4 + reg.

template <int K, bool XF16>
__global__ __launch_bounds__(256, 3)
void gemm_mfma(const void* __restrict__ Xv, const float* __restrict__ W,
               const float* __restrict__ al, const float* __restrict__ ar,
               __half* __restrict__ H2, float* __restrict__ el, float* __restrict__ er,
               int n, int nslabs) {
    constexpr int KS = K / 32;
    int lane = threadIdx.x & 63;
    int li = lane & 15, g = lane >> 4;
    int wid = blockIdx.x * 4 + (threadIdx.x >> 6);
    int wstride = gridDim.x * 4;

    // B fragments + epilogue vectors
    half8_t bf[4][KS];
    float alv[4], arv[4];
#pragma unroll
    for (int ct = 0; ct < 4; ++ct) {
        int col = ct * 16 + li;
        alv[ct] = al[col];
        arv[ct] = ar[col];
#pragma unroll
        for (int ks = 0; ks < KS; ++ks) {
            half8_t b;
#pragma unroll
            for (int j = 0; j < 4; ++j) {
                b[j]     = (_Float16)W[(ks * 32 + 4 * g + j) * 64 + col];
                b[4 + j] = (_Float16)W[(ks * 32 + 16 + 4 * g + j) * 64 + col];
            }
            bf[ct][ks] = b;
        }
    }

    for (int s = wid; s < nslabs; s += wstride) {
        int row = s * 16 + li;
        int rc = row < n ? row : n - 1;

        half8_t a[KS];
#pragma unroll
        for (int ks = 0; ks < KS; ++ks) {
            if constexpr (XF16) {
                const __half* Xh = (const __half*)Xv;
                half4_t h0 = *(const half4_t*)(Xh + (size_t)rc * K + ks * 32 + 4 * g);
                half4_t h1 = *(const half4_t*)(Xh + (size_t)rc * K + ks * 32 + 16 + 4 * g);
                half8_t av;
#pragma unroll
                for (int j = 0; j < 4; ++j) { av[j] = h0[j]; av[4 + j] = h1[j]; }
                a[ks] = av;
            } else {
                const float* Xf = (const float*)Xv;
                float4 v0 = *(const float4*)(Xf + (size_t)rc * K + ks * 32 + 4 * g);
                float4 v1 = *(const float4*)(Xf + (size_t)rc * K + ks * 32 + 16 + 4 * g);
                half8_t av;
                av[0] = (_Float16)v0.x; av[1] = (_Float16)v0.y;
                av[2] = (_Float16)v0.z; av[3] = (_Float16)v0.w;
                av[4] = (_Float16)v1.x; av[5] = (_Float16)v1.y;
                av[6] = (_Float16)v1.z; av[7] = (_Float16)v1.w;
                a[ks] = av;
            }
        }

        floatx4 acc[4];
#pragma unroll
        for (int ct = 0; ct < 4; ++ct) acc[ct] = (floatx4){0.f, 0.f, 0.f, 0.f};
#pragma unroll
        for (int ks = 0; ks < KS; ++ks)
#pragma unroll
            for (int ct = 0; ct < 4; ++ct)
                acc[ct] = __builtin_amdgcn_mfma_f32_16x16x32_f16(a[ks], bf[ct][ks], acc[ct], 0, 0, 0);

        // epilogue: el/er row-dots + fp16 H2 store
        float pl[4], pr[4];
#pragma unroll
        for (int r = 0; r < 4; ++r) {
            pl[r] = acc[0][r] * alv[0] + acc[1][r] * alv[1] + acc[2][r] * alv[2] + acc[3][r] * alv[3];
            pr[r] = acc[0][r] * arv[0] + acc[1][r] * arv[1] + acc[2][r] * arv[2] + acc[3][r] * arv[3];
        }
#pragma unroll
        for (int r = 0; r < 4; ++r)
#pragma unroll
            for (int off = 1; off < 16; off <<= 1) {
                pl[r] += __shfl_xor(pl[r], off);
                pr[r] += __shfl_xor(pr[r], off);
            }
        int rowbase = s * 16 + 4 * g;
#pragma unroll
        for (int r = 0; r < 4; ++r) {
            int ro = rowbase + r;
            if (ro < n) {
#pragma unroll
                for (int ct = 0; ct < 4; ++ct)
                    H2[(size_t)ro * HF + ct * 16 + li] = __float2half(acc[ct][r]);
                if (li == 0) { el[ro] = pl[r]; er[ro] = pr[r]; }
            }
        }
    }
}

// ---------------- Edge phase ----------------
template <bool YF16>
__device__ __forceinline__
void node_fullwave(int node, const int* __restrict__ row_ptr, const int* __restrict__ ssrc,
                   const float* __restrict__ el, const float* __restrict__ er,
                   const uint2* __restrict__ H2v, const __half* __restrict__ H2,
                   float4 bv, const float* __restrict__ b, void* __restrict__ Y,
                   int lane, int g, int fl) {
    int s0 = row_ptr[node], s1 = row_ptr[node + 1];
    int d = s1 - s0;
    float ern = er[node];

    if (d <= 64) {
        int sidx = 0;
        float e = -INFINITY;
        if (lane < d) {
            sidx = ssrc[s0 + lane];
            e = el[sidx] + ern;
            e = e > 0.f ? e : LEAKY * e;
        }
        float m = e;
#pragma unroll
        for (int off = 32; off; off >>= 1) m = fmaxf(m, __shfl_xor(m, off));
        float p = (lane < d) ? __expf(e - m) : 0.f;
        float psum = p;
#pragma unroll
        for (int off = 32; off; off >>= 1) psum += __shfl_xor(psum, off);

        float4 acc = make_float4(0.f, 0.f, 0.f, 0.f);
        int nchunk = (d + 31) >> 5;
        for (int c = 0; c < nchunk; ++c) {
            int jb = c * 32 + g;
            int ss[8];
            float pp[8];
#pragma unroll
            for (int u = 0; u < 8; ++u) {
                ss[u] = __shfl(sidx, jb + 4 * u);
                pp[u] = __shfl(p, jb + 4 * u);
            }
            uint2 vv[8];
#pragma unroll
            for (int u = 0; u < 8; ++u) vv[u] = H2v[(size_t)ss[u] * 16 + fl];
#pragma unroll
            for (int u = 0; u < 8; ++u) {
                __half2 a = *(__half2*)&vv[u].x;
                __half2 b2 = *(__half2*)&vv[u].y;
                float2 fa = __half22float2(a);
                float2 fb = __half22float2(b2);
                acc.x = fmaf(pp[u], fa.x, acc.x);
                acc.y = fmaf(pp[u], fa.y, acc.y);
                acc.z = fmaf(pp[u], fb.x, acc.z);
                acc.w = fmaf(pp[u], fb.y, acc.w);
            }
        }
#pragma unroll
        for (int off = 16; off <= 32; off <<= 1) {
            acc.x += __shfl_xor(acc.x, off);
            acc.y += __shfl_xor(acc.y, off);
            acc.z += __shfl_xor(acc.z, off);
            acc.w += __shfl_xor(acc.w, off);
        }
        float inv = d ? 1.f / psum : 0.f;
        float4 o;
        o.x = fmaf(acc.x, inv, bv.x);
        o.y = fmaf(acc.y, inv, bv.y);
        o.z = fmaf(acc.z, inv, bv.z);
        o.w = fmaf(acc.w, inv, bv.w);
        o.x = o.x > 0.f ? o.x : 0.f;
        o.y = o.y > 0.f ? o.y : 0.f;
        o.z = o.z > 0.f ? o.z : 0.f;
        o.w = o.w > 0.f ? o.w : 0.f;
        if (g == 0) {
            if constexpr (YF16) {
                __half2 a = __floats2half2_rn(o.x, o.y);
                __half2 c = __floats2half2_rn(o.z, o.w);
                ((uint2*)Y)[(size_t)node * 16 + fl] = make_uint2(*(unsigned*)&a, *(unsigned*)&c);
            } else {
                ((float4*)Y)[(size_t)node * 16 + fl] = o;
            }
        }
    } else {
        float m = -INFINITY;
        for (int j = s0 + lane; j < s1; j += 64) {
            float e = el[ssrc[j]] + ern;
            e = e > 0.f ? e : LEAKY * e;
            m = fmaxf(m, e);
        }
#pragma unroll
        for (int off = 32; off; off >>= 1) m = fmaxf(m, __shfl_xor(m, off));
        float acc = 0.f, psum = 0.f;
        for (int j = s0; j < s1; ++j) {
            int s = ssrc[j];
            float e = el[s] + ern;
            e = e > 0.f ? e : LEAKY * e;
            float p = __expf(e - m);
            psum += p;
            acc = fmaf(p, __half2float(H2[(size_t)s * HF + lane]), acc);
        }
        float o = acc / psum + b[lane];
        o = o > 0.f ? o : 0.f;
        if constexpr (YF16)
            ((__half*)Y)[(size_t)node * HF + lane] = __float2half(o);
        else
            ((float*)Y)[(size_t)node * HF + lane] = o;
    }
}

// Two nodes per wave (half-wave each); groups 0-1 node A, 2-3 node B.
template <bool YF16>
__global__ __launch_bounds__(256)
void edge_kernel(const int* __restrict__ row_ptr, const int* __restrict__ ssrc,
                 const float* __restrict__ el, const float* __restrict__ er,
                 const __half* __restrict__ H2, const float* __restrict__ b,
                 void* __restrict__ Y, int n) {
    int wave = threadIdx.x >> 6, lane = threadIdx.x & 63;
    int half = lane >> 5, hl = lane & 31;
    int g = lane >> 4, fl = lane & 15;
    const uint2* H2v = (const uint2*)H2;
    float4 bv = ((const float4*)b)[fl];
    int npairs = (n + 1) >> 1;

    for (int pr = blockIdx.x * 4 + wave; pr < npairs; pr += gridDim.x * 4) {
        int nodeA = pr * 2;
        int myNode = nodeA + half;
        bool ok = myNode < n;
        int s0 = 0, d = 0;
        if (ok) {
            s0 = row_ptr[myNode];
            d = row_ptr[myNode + 1] - s0;
        }
        int dA = __shfl(d, 0), dB = __shfl(d, 32);

        if (dA <= 32 && dB <= 32) {
            float ern = ok ? er[myNode] : 0.f;
            int sidx = 0;
            float e = -INFINITY;
            if (hl < d) {
                sidx = ssrc[s0 + hl];
                e = el[sidx] + ern;
                e = e > 0.f ? e : LEAKY * e;
            }
            float m = e;
#pragma unroll
            for (int off = 16; off; off >>= 1) m = fmaxf(m, __shfl_xor(m, off));
            float p = (hl < d) ? __expf(e - m) : 0.f;
            float psum = p;
#pragma unroll
            for (int off = 16; off; off >>= 1) psum += __shfl_xor(psum, off);

            float4 acc = make_float4(0.f, 0.f, 0.f, 0.f);
            int dg = (g >> 1) ? dB : dA;
            int hbase = (g >> 1) << 5;
            int gpar = g & 1;
            int nch = (dg + 15) >> 4;
            for (int c = 0; c < nch; ++c) {
                int ss[8];
                float pp[8];
#pragma unroll
                for (int u = 0; u < 8; ++u) {
                    int sl = hbase + c * 16 + 2 * u + gpar;
                    ss[u] = __shfl(sidx, sl);
                    pp[u] = __shfl(p, sl);
                }
                uint2 vv[8];
#pragma unroll
                for (int u = 0; u < 8; ++u) vv[u] = H2v[(size_t)ss[u] * 16 + fl];
#pragma unroll
                for (int u = 0; u < 8; ++u) {
                    __half2 a = *(__half2*)&vv[u].x;
                    __half2 b2 = *(__half2*)&vv[u].y;
                    float2 fa = __half22float2(a);
                    float2 fb = __half22float2(b2);
                    acc.x = fmaf(pp[u], fa.x, acc.x);
                    acc.y = fmaf(pp[u], fa.y, acc.y);
                    acc.z = fmaf(pp[u], fb.x, acc.z);
                    acc.w = fmaf(pp[u], fb.y, acc.w);
                }
            }
            acc.x += __shfl_xor(acc.x, 16);
            acc.y += __shfl_xor(acc.y, 16);
            acc.z += __shfl_xor(acc.z, 16);
            acc.w += __shfl_xor(acc.w, 16);
            float inv = d ? 1.f / psum : 0.f;
            float4 o;
            o.x = fmaf(acc.x, inv, bv.x);
            o.y = fmaf(acc.y, inv, bv.y);
            o.z = fmaf(acc.z, inv, bv.z);
            o.w = fmaf(acc.w, inv, bv.w);
            o.x = o.x > 0.f ? o.x : 0.f;
            o.y = o.y > 0.f ? o.y : 0.f;
            o.z = o.z > 0.f ? o.z : 0.f;
            o.w = o.w > 0.f ? o.w : 0.f;
            if (!(g & 1) && ok) {
                if constexpr (YF16) {
                    __half2 a = __floats2half2_rn(o.x, o.y);
                    __half2 c2 = __floats2half2_rn(o.z, o.w);
                    ((uint2*)Y)[(size_t)myNode * 16 + fl] = make_uint2(*(unsigned*)&a, *(unsigned*)&c2);
                } else {
                    ((float4*)Y)[(size_t)myNode * 16 + fl] = o;
                }
            }
        } else {
            node_fullwave<YF16>(nodeA, row_ptr, ssrc, el, er, H2v, H2, bv, b, Y, lane, g, fl);
            if (nodeA + 1 < n)
                node_fullwave<YF16>(nodeA + 1, row_ptr, ssrc, el, er, H2v, H2, bv, b, Y, lane, g, fl);
        }
    }
}

// ---------------- launch ----------------

extern "C" void kernel_launch(void* const* d_in, const int* in_sizes, int n_in,
                              void* d_out, int out_size, void* d_ws, size_t ws_size,
                              hipStream_t stream) {
    const int N = in_sizes[0] / 128;
    const int E = in_sizes[1];
    const int nb = (N + NPB - 1) >> 9;

    const float* in_feat = (const float*)d_in[0];
    const int* src = (const int*)d_in[1];
    const int* dst = (const int*)d_in[2];
    const float* W1 = (const float*)d_in[3];
    const float* al1 = (const float*)d_in[4];
    const float* ar1 = (const float*)d_in[5];
    const float* b1 = (const float*)d_in[6];
    const float* W2 = (const float*)d_in[7];
    const float* al2 = (const float*)d_in[8];
    const float* ar2 = (const float*)d_in[9];
    const float* b2 = (const float*)d_in[10];
    const float* W3 = (const float*)d_in[11];
    const float* al3 = (const float*)d_in[12];
    const float* ar3 = (const float*)d_in[13];
    const float* b3 = (const float*)d_in[14];

    char* ws = (char*)d_ws;
    size_t off = 0;
    auto alloc = [&](size_t bytes) {
        void* p = ws + off;
        off += (bytes + 255) & ~(size_t)255;
        return p;
    };
    int* row_ptr = (int*)alloc(((size_t)N + 1) * 4);
    int* ssrc = (int*)alloc((size_t)E * 4);
    int2* part = (int2*)alloc((size_t)E * 8);
    int* Cmat = (int*)alloc((size_t)MAXNB * NBLK * 4);
    int* Omat = (int*)alloc((size_t)MAXNB * NBLK * 4);
    int* bbase = (int*)alloc(((size_t)MAXNB + 1) * 4);
    float* el = (float*)alloc((size_t)N * 4);
    float* er = (float*)alloc((size_t)N * 4);
    __half* H2buf = (__half*)alloc((size_t)N * HF * 2);
    __half* Y2buf = (__half*)alloc((size_t)N * HF * 2);

    part_count<<<NBLK, 256, 0, stream>>>(dst, Cmat, E, nb);
    scan_offsets<<<1, 256, 0, stream>>>(Cmat, Omat, bbase, E, nb);
    part_scatter<<<NBLK, 256, 0, stream>>>(src, dst, Omat, part, E, nb);
    bucket_csr<<<nb, NPB, 0, stream>>>(part, bbase, row_ptr, ssrc, N, E, nb);

    int nslabs = (N + 15) / 16;
    int gg = 512;                  // mfma gemm blocks (grid-stride over slabs)
    int ge = 2048;                 // persistent edge blocks

    // layer 1 (f32 in, fp16 Y out)
    gemm_mfma<128, false><<<gg, 256, 0, stream>>>(in_feat, W1, al1, ar1, H2buf, el, er, N, nslabs);
    edge_kernel<true><<<ge, 256, 0, stream>>>(row_ptr, ssrc, el, er, H2buf, b1, Y2buf, N);
    // layer 2 (fp16 in, fp16 Y out)
    gemm_mfma<64, true><<<gg, 256, 0, stream>>>(Y2buf, W2, al2, ar2, H2buf, el, er, N, nslabs);
    edge_kernel<true><<<ge, 256, 0, stream>>>(row_ptr, ssrc, el, er, H2buf, b2, Y2buf, N);
    // layer 3 (fp16 in, f32 out to d_out)
    gemm_mfma<64, true><<<gg, 256, 0, stream>>>(Y2buf, W3, al3, ar3, H2buf, el, er, N, nslabs);
    edge_kernel<false><<<ge, 256, 0, stream>>>(row_ptr, ssrc, el, er, H2buf, b3, d_out, N);
}